// Round 1
// baseline (157.387 us; speedup 1.0000x reference)
//
#include <hip/hip_runtime.h>

#define NNZ 32
#define HIDDEN 512

__global__ __launch_bounds__(256) void nnue_fused(
    const int* __restrict__ white_idx, const int* __restrict__ black_idx,
    const int* __restrict__ stm,
    const float* __restrict__ white_vals, const float* __restrict__ black_vals,
    const float* __restrict__ ft_weight, const float* __restrict__ ft_bias,
    const float* __restrict__ d1_w, const float* __restrict__ d1_b,
    const float* __restrict__ d2_w, const float* __restrict__ d2_b,
    const float* __restrict__ out_w, const float* __restrict__ out_b,
    float* __restrict__ out)
{
    const int b   = blockIdx.x;
    const int tid = threadIdx.x;

    __shared__ int   s_idx[64];
    __shared__ float s_val[64];
    __shared__ float xs[HIDDEN];
    __shared__ float part[32][9];   // +1 pad on inner dim vs 8 to dodge bank aliasing
    __shared__ float h1s[32];
    __shared__ float h2s[32];

    // ---- stage indices/values (white in [0,32), black in [32,64)) ----
    if (tid < 64) {
        const int side = tid >> 5;
        const int n    = tid & 31;
        const int*   ip = side ? black_idx  : white_idx;
        const float* vp = side ? black_vals : white_vals;
        int   id = ip[b * NNZ + n];
        float v  = vp[b * NNZ + n];
        if (id < 0) { id = 0; v = 0.f; }   // masked-out feature: exact zero contribution
        s_idx[tid] = id;
        s_val[tid] = v;
    }
    __syncthreads();

    // ---- feature transform: each thread owns hidden dims 2*tid, 2*tid+1 ----
    const float2* W = reinterpret_cast<const float2*>(ft_weight);
    float2 accW = make_float2(0.f, 0.f);
    float2 accB = make_float2(0.f, 0.f);
    #pragma unroll 8
    for (int n = 0; n < NNZ; ++n) {
        const float2 w0 = W[(size_t)s_idx[n]      * (HIDDEN / 2) + tid];
        const float2 w1 = W[(size_t)s_idx[32 + n] * (HIDDEN / 2) + tid];
        const float vw = s_val[n];
        const float vb = s_val[32 + n];
        accW.x = fmaf(vw, w0.x, accW.x);
        accW.y = fmaf(vw, w0.y, accW.y);
        accB.x = fmaf(vb, w1.x, accB.x);
        accB.y = fmaf(vb, w1.y, accB.y);
    }

    // ---- us/them combine + relu + scale ----
    const float sgn   = (stm[b] == 0) ? 1.f : -1.f;   // us = white if stm==0
    const float inv64 = 1.0f / 64.0f;
    xs[2 * tid]     = fmaxf(sgn * (accW.x - accB.x) * inv64, 0.f);
    xs[2 * tid + 1] = fmaxf(sgn * (accW.y - accB.y) * inv64, 0.f);
    __syncthreads();

    // ---- layer 1: 32 outputs, dot over 512; 8 partial-summers per output ----
    {
        const int o = tid & 31;
        const int j = tid >> 5;
        const float* w1p = d1_w + o * HIDDEN + j * 64;
        const float* xp  = xs + j * 64;
        float p = 0.f;
        #pragma unroll
        for (int k = 0; k < 64; ++k) p = fmaf(xp[k], w1p[k], p);
        part[o][j] = p;
    }
    __syncthreads();
    if (tid < 32) {
        float s = d1_b[tid];
        #pragma unroll
        for (int j = 0; j < 8; ++j) s += part[tid][j];
        h1s[tid] = fmaxf(s * inv64, 0.f);
    }
    __syncthreads();

    // ---- layer 2: 32x32 ----
    if (tid < 32) {
        const float* w2p = d2_w + tid * 32;
        float s = d2_b[tid];
        #pragma unroll
        for (int k = 0; k < 32; ++k) s = fmaf(h1s[k], w2p[k], s);
        h2s[tid] = fmaxf(s * inv64, 0.f);
    }
    __syncthreads();

    // ---- output head ----
    if (tid == 0) {
        float s = out_b[0];
        #pragma unroll
        for (int k = 0; k < 32; ++k) s = fmaf(h2s[k], out_w[k], s);
        out[b] = s * (1.0f / 16.0f);
    }
}

extern "C" void kernel_launch(void* const* d_in, const int* in_sizes, int n_in,
                              void* d_out, int out_size, void* d_ws, size_t ws_size,
                              hipStream_t stream) {
    const int*   white_idx  = (const int*)d_in[0];
    const int*   black_idx  = (const int*)d_in[1];
    const int*   stm        = (const int*)d_in[2];
    const float* white_vals = (const float*)d_in[3];
    const float* black_vals = (const float*)d_in[4];
    const float* ft_weight  = (const float*)d_in[5];
    const float* ft_bias    = (const float*)d_in[6];
    const float* d1_w       = (const float*)d_in[7];
    const float* d1_b       = (const float*)d_in[8];
    const float* d2_w       = (const float*)d_in[9];
    const float* d2_b       = (const float*)d_in[10];
    const float* out_w      = (const float*)d_in[11];
    const float* out_b      = (const float*)d_in[12];
    float*       out        = (float*)d_out;

    const int B = in_sizes[2];   // stm is [B]
    nnue_fused<<<B, 256, 0, stream>>>(white_idx, black_idx, stm,
                                      white_vals, black_vals,
                                      ft_weight, ft_bias,
                                      d1_w, d1_b, d2_w, d2_b,
                                      out_w, out_b, out);
}

// Round 2
// 149.465 us; speedup vs baseline: 1.0530x; 1.0530x over previous
//
#include <hip/hip_runtime.h>

#define NNZ 32
#define HIDDEN 512

__global__ __launch_bounds__(256) void nnue_fused(
    const int* __restrict__ white_idx, const int* __restrict__ black_idx,
    const int* __restrict__ stm,
    const float* __restrict__ white_vals, const float* __restrict__ black_vals,
    const float* __restrict__ ft_weight, const float* __restrict__ ft_bias,
    const float* __restrict__ d1_w, const float* __restrict__ d1_b,
    const float* __restrict__ d2_w, const float* __restrict__ d2_b,
    const float* __restrict__ out_w, const float* __restrict__ out_b,
    float* __restrict__ out)
{
    const int b   = blockIdx.x;
    const int tid = threadIdx.x;

    __shared__ int   s_idx[64];
    __shared__ float s_val[64];
    __shared__ float s_accB[HIDDEN];
    __shared__ float xs[HIDDEN];
    __shared__ float part[32][9];
    __shared__ float h1s[32];
    __shared__ float h2s[32];

    // ---- stage indices/values (white in [0,32), black in [32,64)) ----
    if (tid < 64) {
        const int sd = tid >> 5;
        const int n  = tid & 31;
        const int*   ip = sd ? black_idx  : white_idx;
        const float* vp = sd ? black_vals : white_vals;
        int   id = ip[b * NNZ + n];
        float v  = vp[b * NNZ + n];
        if (id < 0) { id = 0; v = 0.f; }   // masked feature: exact zero contribution
        s_idx[tid] = id;
        s_val[tid] = v;
    }
    __syncthreads();

    // ---- feature transform ----
    // threads [0,128): white row, thread owns dims [4*lane, 4*lane+4)
    // threads [128,256): black row, same dim ownership
    const int side = tid >> 7;
    const int lane = tid & 127;
    const int base = side << 5;

    const float4* W = reinterpret_cast<const float4*>(ft_weight);
    float4 acc = make_float4(0.f, 0.f, 0.f, 0.f);

    #pragma unroll
    for (int c = 0; c < NNZ; c += 8) {
        float4 w[8];
        float  vv[8];
        #pragma unroll
        for (int u = 0; u < 8; ++u) {
            const int n = base + c + u;
            w[u]  = W[(size_t)s_idx[n] * (HIDDEN / 4) + lane];
            vv[u] = s_val[n];
        }
        #pragma unroll
        for (int u = 0; u < 8; ++u) {
            acc.x = fmaf(vv[u], w[u].x, acc.x);
            acc.y = fmaf(vv[u], w[u].y, acc.y);
            acc.z = fmaf(vv[u], w[u].z, acc.z);
            acc.w = fmaf(vv[u], w[u].w, acc.w);
        }
    }

    // black half publishes its accumulator
    if (side == 1) {
        reinterpret_cast<float4*>(s_accB)[lane] = acc;
    }
    __syncthreads();

    // white half combines: us/them select + relu + scale
    if (side == 0) {
        const float4 aB  = reinterpret_cast<const float4*>(s_accB)[lane];
        const float sgn  = (stm[b] == 0) ? 1.f : -1.f;   // us = white if stm==0
        const float inv64 = 1.0f / 64.0f;
        float4 x;
        x.x = fmaxf(sgn * (acc.x - aB.x) * inv64, 0.f);
        x.y = fmaxf(sgn * (acc.y - aB.y) * inv64, 0.f);
        x.z = fmaxf(sgn * (acc.z - aB.z) * inv64, 0.f);
        x.w = fmaxf(sgn * (acc.w - aB.w) * inv64, 0.f);
        reinterpret_cast<float4*>(xs)[lane] = x;
    }
    __syncthreads();

    // ---- layer 1: 32 outputs, dot over 512; 8 partial-summers per output ----
    {
        const int o = tid & 31;
        const int j = tid >> 5;
        const float* w1p = d1_w + o * HIDDEN + j * 64;
        const float* xp  = xs + j * 64;
        float p = 0.f;
        #pragma unroll
        for (int k = 0; k < 64; ++k) p = fmaf(xp[k], w1p[k], p);
        part[o][j] = p;
    }
    __syncthreads();
    if (tid < 32) {
        const float inv64 = 1.0f / 64.0f;
        float s = d1_b[tid];
        #pragma unroll
        for (int j = 0; j < 8; ++j) s += part[tid][j];
        h1s[tid] = fmaxf(s * inv64, 0.f);
    }
    __syncthreads();

    // ---- layer 2: 32x32 ----
    if (tid < 32) {
        const float inv64 = 1.0f / 64.0f;
        const float* w2p = d2_w + tid * 32;
        float s = d2_b[tid];
        #pragma unroll
        for (int k = 0; k < 32; ++k) s = fmaf(h1s[k], w2p[k], s);
        h2s[tid] = fmaxf(s * inv64, 0.f);
    }
    __syncthreads();

    // ---- output head ----
    if (tid == 0) {
        float s = out_b[0];
        #pragma unroll
        for (int k = 0; k < 32; ++k) s = fmaf(h2s[k], out_w[k], s);
        out[b] = s * (1.0f / 16.0f);
    }
}

extern "C" void kernel_launch(void* const* d_in, const int* in_sizes, int n_in,
                              void* d_out, int out_size, void* d_ws, size_t ws_size,
                              hipStream_t stream) {
    const int*   white_idx  = (const int*)d_in[0];
    const int*   black_idx  = (const int*)d_in[1];
    const int*   stm        = (const int*)d_in[2];
    const float* white_vals = (const float*)d_in[3];
    const float* black_vals = (const float*)d_in[4];
    const float* ft_weight  = (const float*)d_in[5];
    const float* ft_bias    = (const float*)d_in[6];
    const float* d1_w       = (const float*)d_in[7];
    const float* d1_b       = (const float*)d_in[8];
    const float* d2_w       = (const float*)d_in[9];
    const float* d2_b       = (const float*)d_in[10];
    const float* out_w      = (const float*)d_in[11];
    const float* out_b      = (const float*)d_in[12];
    float*       out        = (float*)d_out;

    const int B = in_sizes[2];   // stm is [B]
    nnue_fused<<<B, 256, 0, stream>>>(white_idx, black_idx, stm,
                                      white_vals, black_vals,
                                      ft_weight, ft_bias,
                                      d1_w, d1_b, d2_w, d2_b,
                                      out_w, out_b, out);
}

// Round 3
// 144.156 us; speedup vs baseline: 1.0918x; 1.0368x over previous
//
#include <hip/hip_runtime.h>

#define NNZ 32
#define HIDDEN 512

// ---------------- fp32 -> bf16 (RNE) table compression into d_ws ----------------
__global__ __launch_bounds__(256) void cvt_bf16(const uint4* __restrict__ in,
                                                uint2* __restrict__ out, int n4)
{
    const int i = blockIdx.x * 256 + threadIdx.x;
    if (i >= n4) return;
    uint4 v = in[i];
    #define CV(u) (((u) + 0x7FFFu + (((u) >> 16) & 1u)) >> 16)
    uint2 o;
    o.x = CV(v.x) | (CV(v.y) << 16);
    o.y = CV(v.z) | (CV(v.w) << 16);
    #undef CV
    out[i] = o;
}

// ---------------- fused NNUE forward, bf16 table in d_ws ----------------
__global__ __launch_bounds__(256) void nnue_fused_bf16(
    const int* __restrict__ white_idx, const int* __restrict__ black_idx,
    const int* __restrict__ stm,
    const float* __restrict__ white_vals, const float* __restrict__ black_vals,
    const unsigned* __restrict__ Wt,   // bf16 table, row-major [F][512], packed 2/u32
    const float* __restrict__ d1_w, const float* __restrict__ d1_b,
    const float* __restrict__ d2_w, const float* __restrict__ d2_b,
    const float* __restrict__ out_w, const float* __restrict__ out_b,
    float* __restrict__ out)
{
    const int b   = blockIdx.x;
    const int tid = threadIdx.x;

    __shared__ int   s_idx[64];
    __shared__ float s_val[64];
    __shared__ float s_accB[HIDDEN];
    __shared__ float xs[HIDDEN];
    __shared__ float part[32][9];
    __shared__ float h1s[32];
    __shared__ float h2s[32];

    if (tid < 64) {
        const int sd = tid >> 5;
        const int n  = tid & 31;
        const int*   ip = sd ? black_idx  : white_idx;
        const float* vp = sd ? black_vals : white_vals;
        int   id = ip[b * NNZ + n];
        float v  = vp[b * NNZ + n];
        if (id < 0) { id = 0; v = 0.f; }
        s_idx[tid] = id;
        s_val[tid] = v;
    }
    __syncthreads();

    // threads [0,128): white rows; [128,256): black rows. Thread owns dims [4*lane,4*lane+4).
    const int side = tid >> 7;
    const int lane = tid & 127;
    const int base = side << 5;

    const uint2* W = reinterpret_cast<const uint2*>(Wt); // row = 128 uint2
    float4 acc = make_float4(0.f, 0.f, 0.f, 0.f);

    #pragma unroll
    for (int c = 0; c < NNZ; c += 8) {
        uint2 w[8];
        float vv[8];
        #pragma unroll
        for (int u = 0; u < 8; ++u) {
            const int n = base + c + u;
            w[u]  = W[(size_t)s_idx[n] * 128 + lane];
            vv[u] = s_val[n];
        }
        #pragma unroll
        for (int u = 0; u < 8; ++u) {
            acc.x = fmaf(vv[u], __uint_as_float(w[u].x << 16),          acc.x);
            acc.y = fmaf(vv[u], __uint_as_float(w[u].x & 0xFFFF0000u),  acc.y);
            acc.z = fmaf(vv[u], __uint_as_float(w[u].y << 16),          acc.z);
            acc.w = fmaf(vv[u], __uint_as_float(w[u].y & 0xFFFF0000u),  acc.w);
        }
    }

    if (side == 1) reinterpret_cast<float4*>(s_accB)[lane] = acc;
    __syncthreads();

    if (side == 0) {
        const float4 aB  = reinterpret_cast<const float4*>(s_accB)[lane];
        const float sgn  = (stm[b] == 0) ? 1.f : -1.f;
        const float inv64 = 1.0f / 64.0f;
        float4 x;
        x.x = fmaxf(sgn * (acc.x - aB.x) * inv64, 0.f);
        x.y = fmaxf(sgn * (acc.y - aB.y) * inv64, 0.f);
        x.z = fmaxf(sgn * (acc.z - aB.z) * inv64, 0.f);
        x.w = fmaxf(sgn * (acc.w - aB.w) * inv64, 0.f);
        reinterpret_cast<float4*>(xs)[lane] = x;
    }
    __syncthreads();

    {
        const int o = tid & 31;
        const int j = tid >> 5;
        const float* w1p = d1_w + o * HIDDEN + j * 64;
        const float* xp  = xs + j * 64;
        float p = 0.f;
        #pragma unroll
        for (int k = 0; k < 64; ++k) p = fmaf(xp[k], w1p[k], p);
        part[o][j] = p;
    }
    __syncthreads();
    if (tid < 32) {
        const float inv64 = 1.0f / 64.0f;
        float s = d1_b[tid];
        #pragma unroll
        for (int j = 0; j < 8; ++j) s += part[tid][j];
        h1s[tid] = fmaxf(s * inv64, 0.f);
    }
    __syncthreads();
    if (tid < 32) {
        const float inv64 = 1.0f / 64.0f;
        const float* w2p = d2_w + tid * 32;
        float s = d2_b[tid];
        #pragma unroll
        for (int k = 0; k < 32; ++k) s = fmaf(h1s[k], w2p[k], s);
        h2s[tid] = fmaxf(s * inv64, 0.f);
    }
    __syncthreads();
    if (tid == 0) {
        float s = out_b[0];
        #pragma unroll
        for (int k = 0; k < 32; ++k) s = fmaf(h2s[k], out_w[k], s);
        out[b] = s * (1.0f / 16.0f);
    }
}

// ---------------- fp32 fallback (round-2 kernel) if d_ws too small ----------------
__global__ __launch_bounds__(256) void nnue_fused_f32(
    const int* __restrict__ white_idx, const int* __restrict__ black_idx,
    const int* __restrict__ stm,
    const float* __restrict__ white_vals, const float* __restrict__ black_vals,
    const float* __restrict__ ft_weight,
    const float* __restrict__ d1_w, const float* __restrict__ d1_b,
    const float* __restrict__ d2_w, const float* __restrict__ d2_b,
    const float* __restrict__ out_w, const float* __restrict__ out_b,
    float* __restrict__ out)
{
    const int b   = blockIdx.x;
    const int tid = threadIdx.x;

    __shared__ int   s_idx[64];
    __shared__ float s_val[64];
    __shared__ float s_accB[HIDDEN];
    __shared__ float xs[HIDDEN];
    __shared__ float part[32][9];
    __shared__ float h1s[32];
    __shared__ float h2s[32];

    if (tid < 64) {
        const int sd = tid >> 5;
        const int n  = tid & 31;
        const int*   ip = sd ? black_idx  : white_idx;
        const float* vp = sd ? black_vals : white_vals;
        int   id = ip[b * NNZ + n];
        float v  = vp[b * NNZ + n];
        if (id < 0) { id = 0; v = 0.f; }
        s_idx[tid] = id;
        s_val[tid] = v;
    }
    __syncthreads();

    const int side = tid >> 7;
    const int lane = tid & 127;
    const int base = side << 5;

    const float4* W = reinterpret_cast<const float4*>(ft_weight);
    float4 acc = make_float4(0.f, 0.f, 0.f, 0.f);
    #pragma unroll
    for (int c = 0; c < NNZ; c += 8) {
        float4 w[8];
        float  vv[8];
        #pragma unroll
        for (int u = 0; u < 8; ++u) {
            const int n = base + c + u;
            w[u]  = W[(size_t)s_idx[n] * (HIDDEN / 4) + lane];
            vv[u] = s_val[n];
        }
        #pragma unroll
        for (int u = 0; u < 8; ++u) {
            acc.x = fmaf(vv[u], w[u].x, acc.x);
            acc.y = fmaf(vv[u], w[u].y, acc.y);
            acc.z = fmaf(vv[u], w[u].z, acc.z);
            acc.w = fmaf(vv[u], w[u].w, acc.w);
        }
    }

    if (side == 1) reinterpret_cast<float4*>(s_accB)[lane] = acc;
    __syncthreads();
    if (side == 0) {
        const float4 aB  = reinterpret_cast<const float4*>(s_accB)[lane];
        const float sgn  = (stm[b] == 0) ? 1.f : -1.f;
        const float inv64 = 1.0f / 64.0f;
        float4 x;
        x.x = fmaxf(sgn * (acc.x - aB.x) * inv64, 0.f);
        x.y = fmaxf(sgn * (acc.y - aB.y) * inv64, 0.f);
        x.z = fmaxf(sgn * (acc.z - aB.z) * inv64, 0.f);
        x.w = fmaxf(sgn * (acc.w - aB.w) * inv64, 0.f);
        reinterpret_cast<float4*>(xs)[lane] = x;
    }
    __syncthreads();
    {
        const int o = tid & 31;
        const int j = tid >> 5;
        const float* w1p = d1_w + o * HIDDEN + j * 64;
        const float* xp  = xs + j * 64;
        float p = 0.f;
        #pragma unroll
        for (int k = 0; k < 64; ++k) p = fmaf(xp[k], w1p[k], p);
        part[o][j] = p;
    }
    __syncthreads();
    if (tid < 32) {
        const float inv64 = 1.0f / 64.0f;
        float s = d1_b[tid];
        #pragma unroll
        for (int j = 0; j < 8; ++j) s += part[tid][j];
        h1s[tid] = fmaxf(s * inv64, 0.f);
    }
    __syncthreads();
    if (tid < 32) {
        const float inv64 = 1.0f / 64.0f;
        const float* w2p = d2_w + tid * 32;
        float s = d2_b[tid];
        #pragma unroll
        for (int k = 0; k < 32; ++k) s = fmaf(h1s[k], w2p[k], s);
        h2s[tid] = fmaxf(s * inv64, 0.f);
    }
    __syncthreads();
    if (tid == 0) {
        float s = out_b[0];
        #pragma unroll
        for (int k = 0; k < 32; ++k) s = fmaf(h2s[k], out_w[k], s);
        out[b] = s * (1.0f / 16.0f);
    }
}

extern "C" void kernel_launch(void* const* d_in, const int* in_sizes, int n_in,
                              void* d_out, int out_size, void* d_ws, size_t ws_size,
                              hipStream_t stream) {
    const int*   white_idx  = (const int*)d_in[0];
    const int*   black_idx  = (const int*)d_in[1];
    const int*   stm        = (const int*)d_in[2];
    const float* white_vals = (const float*)d_in[3];
    const float* black_vals = (const float*)d_in[4];
    const float* ft_weight  = (const float*)d_in[5];
    const float* d1_w       = (const float*)d_in[7];
    const float* d1_b       = (const float*)d_in[8];
    const float* d2_w       = (const float*)d_in[9];
    const float* d2_b       = (const float*)d_in[10];
    const float* out_w      = (const float*)d_in[11];
    const float* out_b      = (const float*)d_in[12];
    float*       out        = (float*)d_out;

    const int B  = in_sizes[2];            // stm is [B]
    const long long FH = in_sizes[5];      // F * 512 elements

    if (ws_size >= (size_t)FH * 2) {
        // compress table to bf16 in d_ws, then gather at half the bytes
        const int n4 = (int)(FH / 4);
        cvt_bf16<<<(n4 + 255) / 256, 256, 0, stream>>>(
            (const uint4*)ft_weight, (uint2*)d_ws, n4);
        nnue_fused_bf16<<<B, 256, 0, stream>>>(white_idx, black_idx, stm,
                                               white_vals, black_vals,
                                               (const unsigned*)d_ws,
                                               d1_w, d1_b, d2_w, d2_b,
                                               out_w, out_b, out);
    } else {
        nnue_fused_f32<<<B, 256, 0, stream>>>(white_idx, black_idx, stm,
                                              white_vals, black_vals,
                                              ft_weight,
                                              d1_w, d1_b, d2_w, d2_b,
                                              out_w, out_b, out);
    }
}